// Round 1
// baseline (12873.207 us; speedup 1.0000x reference)
//
#include <hip/hip_runtime.h>
#include <hip/hip_bf16.h>
#include <math.h>

// Problem constants (fixed by the reference)
#define TT 256   // timesteps
#define BB 256   // batch
#define II 128   // input features (layer 0)
#define HH 512   // hidden
#define OO 128   // output features
#define WW 32    // output window

typedef __bf16 bf16x8 __attribute__((ext_vector_type(8)));
typedef float  f32x4  __attribute__((ext_vector_type(4)));

// ---------------- cast fp32 -> bf16 ----------------
__global__ void cast_f32_bf16(const float* __restrict__ in,
                              __bf16* __restrict__ out, int n) {
    int i = blockIdx.x * 256 + threadIdx.x;
    if (i < n) out[i] = (__bf16)in[i];
}

__device__ __forceinline__ float sigm(float x) { return 1.0f / (1.0f + expf(-x)); }

// ---------------- one LSTM timestep for one layer ----------------
// gates[b, g*512+j] = bias + sum_k in_t[b,k] w_ih[g*512+j,k] + sum_k h_prev[b,k] w_hh[g*512+j,k]
// Block tile: 32 batch x 32 hidden units; wave w (0..3) computes gate w.
// MFMA 16x16x32 bf16: A-frag lane l: row=l&15, k=(l>>4)*8+[0..8)
//                     B-frag lane l: col(n)=l&15, k=(l>>4)*8+[0..8)
//                     D: row(m)=(l>>4)*4+r, col(n)=l&15   [measured m89/m91]
__global__ __launch_bounds__(256) void lstm_step(
    const __bf16* __restrict__ in_t,    // [BB, kin]
    const __bf16* __restrict__ h_prev,  // [BB, HH] (null when first)
    const __bf16* __restrict__ w_ih,    // [4*HH, kin]
    const __bf16* __restrict__ w_hh,    // [4*HH, HH]
    const float*  __restrict__ bias,    // [4*HH]
    float*        __restrict__ c_state, // [BB, HH]
    __bf16*       __restrict__ h_out,   // [BB, HH]
    int kin, int first)
{
    const int b0   = blockIdx.x * 32;       // batch base (grid.x = 8)
    const int j0   = blockIdx.y * 32;       // hidden base (grid.y = 16)
    const int wave = threadIdx.x >> 6;      // gate index: 0=i 1=f 2=g 3=o
    const int lane = threadIdx.x & 63;
    const int arow = lane & 15;
    const int koff = (lane >> 4) * 8;
    const int nbase = wave * HH + j0;       // row base in weight matrices

    f32x4 acc[2][2] = {};

    // ---- input contribution: K = kin ----
    {
        const __bf16* a0p = in_t + (size_t)(b0 + arow) * kin + koff;
        const __bf16* a1p = in_t + (size_t)(b0 + 16 + arow) * kin + koff;
        const __bf16* w0p = w_ih + (size_t)(nbase + arow) * kin + koff;
        const __bf16* w1p = w_ih + (size_t)(nbase + 16 + arow) * kin + koff;
        for (int k0 = 0; k0 < kin; k0 += 32) {
            bf16x8 a0 = *(const bf16x8*)(a0p + k0);
            bf16x8 a1 = *(const bf16x8*)(a1p + k0);
            bf16x8 w0 = *(const bf16x8*)(w0p + k0);
            bf16x8 w1 = *(const bf16x8*)(w1p + k0);
            acc[0][0] = __builtin_amdgcn_mfma_f32_16x16x32_bf16(a0, w0, acc[0][0], 0, 0, 0);
            acc[0][1] = __builtin_amdgcn_mfma_f32_16x16x32_bf16(a0, w1, acc[0][1], 0, 0, 0);
            acc[1][0] = __builtin_amdgcn_mfma_f32_16x16x32_bf16(a1, w0, acc[1][0], 0, 0, 0);
            acc[1][1] = __builtin_amdgcn_mfma_f32_16x16x32_bf16(a1, w1, acc[1][1], 0, 0, 0);
        }
    }
    // ---- recurrent contribution: K = HH (skip at t==0, h0 = 0) ----
    if (!first) {
        const __bf16* a0p = h_prev + (size_t)(b0 + arow) * HH + koff;
        const __bf16* a1p = h_prev + (size_t)(b0 + 16 + arow) * HH + koff;
        const __bf16* w0p = w_hh + (size_t)(nbase + arow) * HH + koff;
        const __bf16* w1p = w_hh + (size_t)(nbase + 16 + arow) * HH + koff;
        for (int k0 = 0; k0 < HH; k0 += 32) {
            bf16x8 a0 = *(const bf16x8*)(a0p + k0);
            bf16x8 a1 = *(const bf16x8*)(a1p + k0);
            bf16x8 w0 = *(const bf16x8*)(w0p + k0);
            bf16x8 w1 = *(const bf16x8*)(w1p + k0);
            acc[0][0] = __builtin_amdgcn_mfma_f32_16x16x32_bf16(a0, w0, acc[0][0], 0, 0, 0);
            acc[0][1] = __builtin_amdgcn_mfma_f32_16x16x32_bf16(a0, w1, acc[0][1], 0, 0, 0);
            acc[1][0] = __builtin_amdgcn_mfma_f32_16x16x32_bf16(a1, w0, acc[1][0], 0, 0, 0);
            acc[1][1] = __builtin_amdgcn_mfma_f32_16x16x32_bf16(a1, w1, acc[1][1], 0, 0, 0);
        }
    }

    // ---- exchange the 4 gate tiles through LDS ----
    __shared__ float g_lds[4][32][33];   // +1 pad
    #pragma unroll
    for (int mi = 0; mi < 2; ++mi)
        #pragma unroll
        for (int ni = 0; ni < 2; ++ni)
            #pragma unroll
            for (int r = 0; r < 4; ++r) {
                int m = mi * 16 + ((lane >> 4) * 4) + r;  // batch within tile
                int n = ni * 16 + (lane & 15);            // hidden within tile
                g_lds[wave][m][n] = acc[mi][ni][r];
            }
    __syncthreads();

    // ---- elementwise cell update (fp32) ----
    for (int idx = threadIdx.x; idx < 32 * 32; idx += 256) {
        int bm = idx >> 5, jn = idx & 31;
        int b = b0 + bm, j = j0 + jn;
        float xi = g_lds[0][bm][jn] + bias[0 * HH + j];
        float xf = g_lds[1][bm][jn] + bias[1 * HH + j];
        float xg = g_lds[2][bm][jn] + bias[2 * HH + j];
        float xo = g_lds[3][bm][jn] + bias[3 * HH + j];
        float iv = sigm(xi);
        float fv = sigm(xf);
        float gv = tanhf(xg);
        float ov = sigm(xo);
        size_t cidx = (size_t)b * HH + j;
        float c = first ? (iv * gv) : fmaf(fv, c_state[cidx], iv * gv);
        c_state[cidx] = c;
        h_out[cidx] = (__bf16)(ov * tanhf(c));
    }
}

// ---------------- final projection: y[r, o] = b_out[o] + sum_k A[r,k] Wo[o,k] ----------------
// A = h2 rows starting at t=TT-WW; M = WW*BB = 8192, N = OO = 128, K = HH
__global__ __launch_bounds__(256) void proj_kernel(
    const __bf16* __restrict__ A,    // [8192, HH]
    const __bf16* __restrict__ Wo,   // [OO, HH]
    const float*  __restrict__ bo,   // [OO]
    float*        __restrict__ out)  // [8192, OO]
{
    const int r0   = blockIdx.x * 32;
    const int wave = threadIdx.x >> 6;
    const int lane = threadIdx.x & 63;
    const int n0   = wave * 32;
    const int arow = lane & 15;
    const int koff = (lane >> 4) * 8;

    f32x4 acc[2][2] = {};
    const __bf16* a0p = A  + (size_t)(r0 + arow) * HH + koff;
    const __bf16* a1p = A  + (size_t)(r0 + 16 + arow) * HH + koff;
    const __bf16* w0p = Wo + (size_t)(n0 + arow) * HH + koff;
    const __bf16* w1p = Wo + (size_t)(n0 + 16 + arow) * HH + koff;
    for (int k0 = 0; k0 < HH; k0 += 32) {
        bf16x8 a0 = *(const bf16x8*)(a0p + k0);
        bf16x8 a1 = *(const bf16x8*)(a1p + k0);
        bf16x8 w0 = *(const bf16x8*)(w0p + k0);
        bf16x8 w1 = *(const bf16x8*)(w1p + k0);
        acc[0][0] = __builtin_amdgcn_mfma_f32_16x16x32_bf16(a0, w0, acc[0][0], 0, 0, 0);
        acc[0][1] = __builtin_amdgcn_mfma_f32_16x16x32_bf16(a0, w1, acc[0][1], 0, 0, 0);
        acc[1][0] = __builtin_amdgcn_mfma_f32_16x16x32_bf16(a1, w0, acc[1][0], 0, 0, 0);
        acc[1][1] = __builtin_amdgcn_mfma_f32_16x16x32_bf16(a1, w1, acc[1][1], 0, 0, 0);
    }
    #pragma unroll
    for (int mi = 0; mi < 2; ++mi)
        #pragma unroll
        for (int ni = 0; ni < 2; ++ni)
            #pragma unroll
            for (int r = 0; r < 4; ++r) {
                int row = r0 + mi * 16 + ((lane >> 4) * 4) + r;
                int col = n0 + ni * 16 + (lane & 15);
                out[(size_t)row * OO + col] = acc[mi][ni][r] + bo[col];
            }
}

// ---------------- launch ----------------
extern "C" void kernel_launch(void* const* d_in, const int* in_sizes, int n_in,
                              void* d_out, int out_size, void* d_ws, size_t ws_size,
                              hipStream_t stream) {
    const float* x      = (const float*)d_in[0];
    const float* w_ih_0 = (const float*)d_in[1];
    const float* w_hh_0 = (const float*)d_in[2];
    const float* b_0    = (const float*)d_in[3];
    const float* w_ih_1 = (const float*)d_in[4];
    const float* w_hh_1 = (const float*)d_in[5];
    const float* b_1    = (const float*)d_in[6];
    const float* w_ih_2 = (const float*)d_in[7];
    const float* w_hh_2 = (const float*)d_in[8];
    const float* b_2    = (const float*)d_in[9];
    const float* w_out  = (const float*)d_in[10];
    const float* b_out  = (const float*)d_in[11];
    float* out = (float*)d_out;

    // ---- workspace carve-up (all bf16 buffers 16B-aligned by construction) ----
    char* ws = (char*)d_ws;
    size_t off = 0;
    __bf16* xb    = (__bf16*)(ws + off); off += (size_t)TT * BB * II * 2;     // 16.8 MB
    __bf16* wih0b = (__bf16*)(ws + off); off += (size_t)4 * HH * II * 2;
    __bf16* whh0b = (__bf16*)(ws + off); off += (size_t)4 * HH * HH * 2;
    __bf16* wih1b = (__bf16*)(ws + off); off += (size_t)4 * HH * HH * 2;
    __bf16* whh1b = (__bf16*)(ws + off); off += (size_t)4 * HH * HH * 2;
    __bf16* wih2b = (__bf16*)(ws + off); off += (size_t)4 * HH * HH * 2;
    __bf16* whh2b = (__bf16*)(ws + off); off += (size_t)4 * HH * HH * 2;
    __bf16* woutb = (__bf16*)(ws + off); off += (size_t)OO * HH * 2;
    __bf16* h0    = (__bf16*)(ws + off); off += (size_t)TT * BB * HH * 2;     // 67 MB
    __bf16* h1    = (__bf16*)(ws + off); off += (size_t)TT * BB * HH * 2;
    __bf16* h2    = (__bf16*)(ws + off); off += (size_t)TT * BB * HH * 2;
    float*  c0    = (float*)(ws + off);  off += (size_t)BB * HH * 4;
    float*  c1    = (float*)(ws + off);  off += (size_t)BB * HH * 4;
    float*  c2    = (float*)(ws + off);  off += (size_t)BB * HH * 4;
    (void)ws_size; (void)in_sizes; (void)n_in; (void)out_size;

    // ---- casts ----
    {
        int n;
        n = TT * BB * II;  cast_f32_bf16<<<(n + 255) / 256, 256, 0, stream>>>(x, xb, n);
        n = 4 * HH * II;   cast_f32_bf16<<<(n + 255) / 256, 256, 0, stream>>>(w_ih_0, wih0b, n);
        n = 4 * HH * HH;   cast_f32_bf16<<<(n + 255) / 256, 256, 0, stream>>>(w_hh_0, whh0b, n);
        n = 4 * HH * HH;   cast_f32_bf16<<<(n + 255) / 256, 256, 0, stream>>>(w_ih_1, wih1b, n);
        n = 4 * HH * HH;   cast_f32_bf16<<<(n + 255) / 256, 256, 0, stream>>>(w_hh_1, whh1b, n);
        n = 4 * HH * HH;   cast_f32_bf16<<<(n + 255) / 256, 256, 0, stream>>>(w_ih_2, wih2b, n);
        n = 4 * HH * HH;   cast_f32_bf16<<<(n + 255) / 256, 256, 0, stream>>>(w_hh_2, whh2b, n);
        n = OO * HH;       cast_f32_bf16<<<(n + 255) / 256, 256, 0, stream>>>(w_out, woutb, n);
    }

    // ---- 3 LSTM layers, sequential over time ----
    const __bf16* wihs[3] = {wih0b, wih1b, wih2b};
    const __bf16* whhs[3] = {whh0b, whh1b, whh2b};
    const float*  bs[3]   = {b_0, b_1, b_2};
    float*        cs[3]   = {c0, c1, c2};
    __bf16*       hs[3]   = {h0, h1, h2};
    const dim3 sgrid(BB / 32, HH / 32);  // 8 x 16 = 128 blocks

    for (int l = 0; l < 3; ++l) {
        const int kin = (l == 0) ? II : HH;
        const __bf16* in_seq = (l == 0) ? xb : hs[l - 1];
        const size_t in_stride = (size_t)BB * kin;
        for (int t = 0; t < TT; ++t) {
            const __bf16* in_t   = in_seq + (size_t)t * in_stride;
            const __bf16* h_prev = (t == 0) ? nullptr : hs[l] + (size_t)(t - 1) * BB * HH;
            __bf16*       h_out  = hs[l] + (size_t)t * BB * HH;
            lstm_step<<<sgrid, 256, 0, stream>>>(in_t, h_prev, wihs[l], whhs[l],
                                                 bs[l], cs[l], h_out, kin, t == 0 ? 1 : 0);
        }
    }

    // ---- projection over last WW timesteps ----
    const __bf16* A = h2 + (size_t)(TT - WW) * BB * HH;
    proj_kernel<<<(WW * BB) / 32, 256, 0, stream>>>(A, woutb, b_out, out);
}

// Round 4
// 3520.922 us; speedup vs baseline: 3.6562x; 3.6562x over previous
//
#include <hip/hip_runtime.h>
#include <hip/hip_bf16.h>
#include <math.h>

// Problem constants (fixed by the reference)
#define TT 256   // timesteps
#define BB 256   // batch
#define II 128   // input features (layer 0)
#define HH 512   // hidden
#define OO 128   // output features
#define WW 32    // output window

// Bounded-spin cap: ~20k sleeps x ~150-500cy >= 2ms, ~1000x any legitimate
// barrier wait. On cap-trip the kernel free-runs (wrong answer, visible in
// absmax) instead of hanging the container.
#define SPIN_CAP 20000

typedef __bf16 bf16x8 __attribute__((ext_vector_type(8)));
typedef float  f32x4  __attribute__((ext_vector_type(4)));

// ---------------- fast gate functions (v_exp_f32 = 2^x, v_rcp_f32) ----------------
__device__ __forceinline__ float fast_sigm(float x) {
    float e = __builtin_amdgcn_exp2f(-1.442695040889f * x);
    return __builtin_amdgcn_rcpf(1.0f + e);
}
__device__ __forceinline__ float fast_tanh(float x) {
    float e = __builtin_amdgcn_exp2f(2.885390081777f * x);
    return 1.0f - 2.0f * __builtin_amdgcn_rcpf(1.0f + e);
}

// ---------------- cast fp32 -> bf16 (plain) ----------------
__global__ void cast_f32_bf16(const float* __restrict__ in,
                              __bf16* __restrict__ out, int n) {
    int i = blockIdx.x * 256 + threadIdx.x;
    if (i < n) out[i] = (__bf16)in[i];
}

// ---------------- weight prepack ----------------
// dst row' = jb*64 + g*16 + jj  <->  orig gate-row = g*512 + jb*16 + jj
// dst row k-layout = [ w_ih (KIN) ; w_hh (512) ]   (bf16, plain)
__global__ void pack_w_kernel(const float* __restrict__ wih,
                              const float* __restrict__ whh,
                              __bf16* __restrict__ dst, int KIN) {
    int idx = blockIdx.x * 256 + threadIdx.x;
    int KE8 = (KIN + 512) >> 3;
    int total = 2048 * KE8;
    if (idx >= total) return;
    int row = idx / KE8, k8 = idx - row * KE8;
    int jb = row >> 6, g = (row >> 4) & 3, jj = row & 15;
    int orig = g * 512 + jb * 16 + jj;
    int k = k8 * 8;
    const float* src = (k < KIN) ? (wih + (size_t)orig * KIN + k)
                                 : (whh + (size_t)orig * 512 + (k - KIN));
    __bf16* d = dst + (size_t)row * (KIN + 512) + k;
    #pragma unroll
    for (int i = 0; i < 8; ++i) d[i] = (__bf16)src[i];
}

// ---------------- global -> LDS staging (linear, row-padded 1024->1040) ----------------
// Each 1024B chunk (one K=512 row, or four K=128 rows) lands at chunk*1040 in LDS.
__device__ __forceinline__ void stage_tile(char* lds, const char* g, int nchunk,
                                           int wv, int l) {
    const int half = nchunk >> 1;
    const char* gp = g + (size_t)l * 16;
    for (int i = 0; i < half; ++i) {
        int c = wv * half + i;
        __builtin_amdgcn_global_load_lds(
            (const __attribute__((address_space(1))) void*)(gp + c * 1024),
            (__attribute__((address_space(3))) void*)(lds + c * 1040),
            16, 0, 0);
    }
}

// ---------------- one LSTM layer, persistent (template: KX = KIN/32) ----------------
template <int KX>
__device__ __forceinline__ void run_layer(
    const __bf16* __restrict__ xsrc,   // [T][B][KX*32] plain bf16
    const __bf16* __restrict__ pw,     // [2048][KX*32+512] packed bf16
    const float*  __restrict__ bias,   // [2048] gate order i,f,g,o
    __bf16*       __restrict__ hout,   // [T][B][512] plain bf16
    int* ctr, int grp, int jb, int tid, int gbase, bool same,
    char* s_x, char* s_h, float (*s_g)[32][17])
{
    const int wv = tid >> 6, l = tid & 63;
    const int KE = KX * 32 + 512;

    // ---- weights -> VGPRs (per wave: 32 gate-rows x K; B-frag native layout) ----
    bf16x8 w[2][KX + 16];
    #pragma unroll
    for (int nt = 0; nt < 2; ++nt) {
        const __bf16* rp = pw + (size_t)(jb * 64 + wv * 32 + nt * 16 + (l & 15)) * KE
                              + (l >> 4) * 8;
        #pragma unroll
        for (int kk = 0; kk < KX + 16; ++kk)
            w[nt][kk] = *(const bf16x8*)(rp + kk * 32);
    }

    // ---- bias + cell state in registers ----
    const int eb = tid >> 2;          // batch-local 0..31
    const int ej = (tid & 3) * 4;     // hidden-local {0,4,8,12}
    float br[4][4], cc[4];
    #pragma unroll
    for (int g = 0; g < 4; ++g)
        #pragma unroll
        for (int q = 0; q < 4; ++q)
            br[g][q] = bias[g * 512 + jb * 16 + ej + q];
    #pragma unroll
    for (int q = 0; q < 4; ++q) cc[q] = 0.0f;

    // ---- per-lane LDS fragment base offsets (padded rows: stride 1040) ----
    const int Cq = (l >> 4) * 16;
    const int row0 = (l & 15), row1 = 16 + (l & 15);
    int xoff0, xoff1;
    if (KX == 4) {   // 256B rows, 4 per chunk
        xoff0 = (row0 >> 2) * 1040 + (row0 & 3) * 256 + Cq;
        xoff1 = (row1 >> 2) * 1040 + (row1 & 3) * 256 + Cq;
    } else {         // 1024B rows, 1 per chunk
        xoff0 = row0 * 1040 + Cq;
        xoff1 = row1 * 1040 + Cq;
    }
    const int hoff0 = row0 * 1040 + Cq, hoff1 = row1 * 1040 + Cq;

    const size_t xrow = (size_t)KX * 64;   // bytes per batch-row of x

    // prologue: stage x(0)
    stage_tile(s_x, (const char*)xsrc + (size_t)(grp * 32) * xrow, KX * 2, wv, l);

    for (int t = 0; t < TT; ++t) {
        if (t > 0)
            stage_tile(s_h, (const char*)hout + (size_t)((t - 1) * 256 + grp * 32) * 1024,
                       32, wv, l);
        __syncthreads();   // drains vmcnt: x- and h-stages complete

        f32x4 acc[2][2] = {};
        #pragma unroll
        for (int kk = 0; kk < KX; ++kk) {
            bf16x8 a0 = *(const bf16x8*)(s_x + xoff0 + kk * 64);
            bf16x8 a1 = *(const bf16x8*)(s_x + xoff1 + kk * 64);
            acc[0][0] = __builtin_amdgcn_mfma_f32_16x16x32_bf16(a0, w[0][kk], acc[0][0], 0, 0, 0);
            acc[0][1] = __builtin_amdgcn_mfma_f32_16x16x32_bf16(a0, w[1][kk], acc[0][1], 0, 0, 0);
            acc[1][0] = __builtin_amdgcn_mfma_f32_16x16x32_bf16(a1, w[0][kk], acc[1][0], 0, 0, 0);
            acc[1][1] = __builtin_amdgcn_mfma_f32_16x16x32_bf16(a1, w[1][kk], acc[1][1], 0, 0, 0);
        }
        if (t > 0) {
            #pragma unroll
            for (int kk = 0; kk < 16; ++kk) {
                bf16x8 a0 = *(const bf16x8*)(s_h + hoff0 + kk * 64);
                bf16x8 a1 = *(const bf16x8*)(s_h + hoff1 + kk * 64);
                acc[0][0] = __builtin_amdgcn_mfma_f32_16x16x32_bf16(a0, w[0][KX + kk], acc[0][0], 0, 0, 0);
                acc[0][1] = __builtin_amdgcn_mfma_f32_16x16x32_bf16(a0, w[1][KX + kk], acc[0][1], 0, 0, 0);
                acc[1][0] = __builtin_amdgcn_mfma_f32_16x16x32_bf16(a1, w[0][KX + kk], acc[1][0], 0, 0, 0);
                acc[1][1] = __builtin_amdgcn_mfma_f32_16x16x32_bf16(a1, w[1][KX + kk], acc[1][1], 0, 0, 0);
            }
        }

        // ---- gate exchange (wave wv holds gates wv*2, wv*2+1) ----
        #pragma unroll
        for (int mt = 0; mt < 2; ++mt)
            #pragma unroll
            for (int nt = 0; nt < 2; ++nt)
                #pragma unroll
                for (int r = 0; r < 4; ++r)
                    s_g[wv * 2 + nt][mt * 16 + (l >> 4) * 4 + r][l & 15] = acc[mt][nt][r];
        __syncthreads();

        // ---- elementwise cell update; c lives in registers ----
        union { __bf16 h4[4]; uint2 u; } pk;
        #pragma unroll
        for (int q = 0; q < 4; ++q) {
            float xi = s_g[0][eb][ej + q] + br[0][q];
            float xf = s_g[1][eb][ej + q] + br[1][q];
            float xg = s_g[2][eb][ej + q] + br[2][q];
            float xo = s_g[3][eb][ej + q] + br[3][q];
            float iv = fast_sigm(xi), fv = fast_sigm(xf);
            float gv = fast_tanh(xg), ov = fast_sigm(xo);
            cc[q] = (t == 0) ? iv * gv : fmaf(fv, cc[q], iv * gv);
            pk.h4[q] = (__bf16)(ov * fast_tanh(cc[q]));
        }
        *(uint2*)((char*)hout +
                  (size_t)((t * 256 + grp * 32 + eb) * 512 + jb * 16 + ej) * 2) = pk.u;

        // ---- group barrier (32 blocks); x(t+1) prefetch overlaps the spin ----
        if (!same) __threadfence();      // cross-XCD release (wbl2)
        __syncthreads();                 // vmcnt(0) drain: h-store visible in L2
        if (tid == 0)
            __hip_atomic_fetch_add(ctr, 1, __ATOMIC_RELAXED, __HIP_MEMORY_SCOPE_AGENT);
        if (t + 1 < TT)
            stage_tile(s_x, (const char*)xsrc + (size_t)((t + 1) * 256 + grp * 32) * xrow,
                       KX * 2, wv, l);
        if (tid == 0) {
            int tgt = 32 * (gbase + t + 1);
            int spins = 0;
            while (__hip_atomic_load(ctr, __ATOMIC_RELAXED, __HIP_MEMORY_SCOPE_AGENT) < tgt) {
                __builtin_amdgcn_s_sleep(2);
                if (++spins > SPIN_CAP) break;   // bounded: fail visibly, never hang
            }
        }
        __syncthreads();
        if (!same) __threadfence();      // cross-XCD acquire (inv)
    }
}

// ---------------- persistent 3-layer LSTM kernel ----------------
__global__ __launch_bounds__(128, 1) void lstm_persist(
    const __bf16* __restrict__ xb,
    const __bf16* __restrict__ pw0, const __bf16* __restrict__ pw1,
    const __bf16* __restrict__ pw2,
    const float* __restrict__ b0, const float* __restrict__ b1,
    const float* __restrict__ b2,
    __bf16* __restrict__ h0, __bf16* __restrict__ h1, __bf16* __restrict__ h2,
    int* ctrA, int* ctrB)
{
    __shared__ __align__(16) char s_x[33280];   // 32 x 1024B rows, 1040B stride
    __shared__ __align__(16) char s_h[33280];
    __shared__ float s_g[4][32][17];
    __shared__ int s_same;

    const int tid = threadIdx.x;
    const int grp = blockIdx.x & 7;      // batch-tile; == XCD under bid%8 mapping
    const int jb  = blockIdx.x >> 3;     // hidden-tile (16 units x 4 gates)

    // ---- runtime same-XCD check (correct either way; fast path if true) ----
    if (tid == 0) {
        unsigned xcc = 0;
        asm volatile("s_getreg_b32 %0, hwreg(HW_REG_XCC_ID)" : "=s"(xcc));
        int* cnt = ctrB + grp * 64;
        int* msk = ctrB + grp * 64 + 16;
        __hip_atomic_fetch_or(msk, 1 << (xcc & 7), __ATOMIC_RELEASE, __HIP_MEMORY_SCOPE_AGENT);
        __hip_atomic_fetch_add(cnt, 1, __ATOMIC_RELEASE, __HIP_MEMORY_SCOPE_AGENT);
        int spins = 0;
        while (__hip_atomic_load(cnt, __ATOMIC_ACQUIRE, __HIP_MEMORY_SCOPE_AGENT) < 32) {
            __builtin_amdgcn_s_sleep(2);
            if (++spins > SPIN_CAP) break;       // bounded: fail visibly, never hang
        }
        int m = __hip_atomic_load(msk, __ATOMIC_ACQUIRE, __HIP_MEMORY_SCOPE_AGENT);
        s_same = (__popc((unsigned)m) == 1) ? 1 : 0;
    }
    __syncthreads();
    const bool same = (s_same != 0);

    run_layer<4>(xb, pw0, b0, h0, ctrA + grp * 64, grp, jb, tid, 0, same, s_x, s_h, s_g);
    run_layer<16>(h0, pw1, b1, h1, ctrA + grp * 64, grp, jb, tid, 256, same, s_x, s_h, s_g);
    run_layer<16>(h1, pw2, b2, h2, ctrA + grp * 64, grp, jb, tid, 512, same, s_x, s_h, s_g);
}

// ---------------- final projection (h2 is plain [8192, HH]) ----------------
__global__ __launch_bounds__(256) void proj_kernel(
    const __bf16* __restrict__ A,    // [8192, HH]
    const __bf16* __restrict__ Wo,   // [OO, HH]
    const float*  __restrict__ bo,   // [OO]
    float*        __restrict__ out)  // [8192, OO]
{
    const int r0   = blockIdx.x * 32;
    const int wave = threadIdx.x >> 6;
    const int lane = threadIdx.x & 63;
    const int n0   = wave * 32;
    const int arow = lane & 15;
    const int koff = (lane >> 4) * 8;

    f32x4 acc[2][2] = {};
    const __bf16* a0p = A  + (size_t)(r0 + arow) * HH + koff;
    const __bf16* a1p = A  + (size_t)(r0 + 16 + arow) * HH + koff;
    const __bf16* w0p = Wo + (size_t)(n0 + arow) * HH + koff;
    const __bf16* w1p = Wo + (size_t)(n0 + 16 + arow) * HH + koff;
    for (int k0 = 0; k0 < HH; k0 += 32) {
        bf16x8 a0 = *(const bf16x8*)(a0p + k0);
        bf16x8 a1 = *(const bf16x8*)(a1p + k0);
        bf16x8 w0 = *(const bf16x8*)(w0p + k0);
        bf16x8 w1 = *(const bf16x8*)(w1p + k0);
        acc[0][0] = __builtin_amdgcn_mfma_f32_16x16x32_bf16(a0, w0, acc[0][0], 0, 0, 0);
        acc[0][1] = __builtin_amdgcn_mfma_f32_16x16x32_bf16(a0, w1, acc[0][1], 0, 0, 0);
        acc[1][0] = __builtin_amdgcn_mfma_f32_16x16x32_bf16(a1, w0, acc[1][0], 0, 0, 0);
        acc[1][1] = __builtin_amdgcn_mfma_f32_16x16x32_bf16(a1, w1, acc[1][1], 0, 0, 0);
    }
    #pragma unroll
    for (int mi = 0; mi < 2; ++mi)
        #pragma unroll
        for (int ni = 0; ni < 2; ++ni)
            #pragma unroll
            for (int r = 0; r < 4; ++r) {
                int row = r0 + mi * 16 + ((lane >> 4) * 4) + r;
                int col = n0 + ni * 16 + (lane & 15);
                out[(size_t)row * OO + col] = acc[mi][ni][r] + bo[col];
            }
}

// ---------------- launch ----------------
extern "C" void kernel_launch(void* const* d_in, const int* in_sizes, int n_in,
                              void* d_out, int out_size, void* d_ws, size_t ws_size,
                              hipStream_t stream) {
    const float* x      = (const float*)d_in[0];
    const float* w_ih_0 = (const float*)d_in[1];
    const float* w_hh_0 = (const float*)d_in[2];
    const float* b_0    = (const float*)d_in[3];
    const float* w_ih_1 = (const float*)d_in[4];
    const float* w_hh_1 = (const float*)d_in[5];
    const float* b_1    = (const float*)d_in[6];
    const float* w_ih_2 = (const float*)d_in[7];
    const float* w_hh_2 = (const float*)d_in[8];
    const float* b_2    = (const float*)d_in[9];
    const float* w_out  = (const float*)d_in[10];
    const float* b_out  = (const float*)d_in[11];
    float* out = (float*)d_out;

    // ---- workspace carve-up ----
    char* ws = (char*)d_ws;
    size_t off = 0;
    __bf16* xb    = (__bf16*)(ws + off); off += (size_t)TT * BB * II * 2;      // 16.8 MB
    __bf16* pw0   = (__bf16*)(ws + off); off += (size_t)2048 * 640 * 2;        // 2.6 MB
    __bf16* pw1   = (__bf16*)(ws + off); off += (size_t)2048 * 1024 * 2;       // 4.2 MB
    __bf16* pw2   = (__bf16*)(ws + off); off += (size_t)2048 * 1024 * 2;
    __bf16* woutb = (__bf16*)(ws + off); off += (size_t)OO * HH * 2;
    __bf16* h0    = (__bf16*)(ws + off); off += (size_t)TT * BB * HH * 2;      // 67 MB
    __bf16* h1    = (__bf16*)(ws + off); off += (size_t)TT * BB * HH * 2;
    __bf16* h2    = (__bf16*)(ws + off); off += (size_t)TT * BB * HH * 2;
    int*    ctrA  = (int*)(ws + off);    off += (size_t)8 * 64 * 4;
    int*    ctrB  = (int*)(ws + off);    off += (size_t)8 * 64 * 4;
    (void)ws_size; (void)in_sizes; (void)n_in; (void)out_size;

    // ---- prepack ----
    {
        int n = TT * BB * II;
        cast_f32_bf16<<<(n + 255) / 256, 256, 0, stream>>>(x, xb, n);
        n = OO * HH;
        cast_f32_bf16<<<(n + 255) / 256, 256, 0, stream>>>(w_out, woutb, n);
        int t0 = 2048 * (640 / 8);
        pack_w_kernel<<<(t0 + 255) / 256, 256, 0, stream>>>(w_ih_0, w_hh_0, pw0, II);
        int t1 = 2048 * (1024 / 8);
        pack_w_kernel<<<(t1 + 255) / 256, 256, 0, stream>>>(w_ih_1, w_hh_1, pw1, HH);
        pack_w_kernel<<<(t1 + 255) / 256, 256, 0, stream>>>(w_ih_2, w_hh_2, pw2, HH);
    }
    hipMemsetAsync(ctrA, 0, (size_t)2 * 8 * 64 * 4, stream);

    // ---- persistent 3-layer LSTM: 256 blocks (1/CU), group-local barriers ----
    lstm_persist<<<256, 128, 0, stream>>>(xb, pw0, pw1, pw2, b_0, b_1, b_2,
                                          h0, h1, h2, ctrA, ctrB);

    // ---- projection over last WW timesteps ----
    const __bf16* A = h2 + (size_t)(TT - WW) * BB * HH;
    proj_kernel<<<(WW * BB) / 32, 256, 0, stream>>>(A, woutb, b_out, out);
}

// Round 5
// 2141.912 us; speedup vs baseline: 6.0101x; 1.6438x over previous
//
#include <hip/hip_runtime.h>
#include <hip/hip_bf16.h>
#include <math.h>

// Problem constants (fixed by the reference)
#define TT 256   // timesteps
#define BB 256   // batch
#define II 128   // input features (layer 0)
#define HH 512   // hidden
#define OO 128   // output features
#define WW 32    // output window

// Bounded-spin cap: on cap-trip the kernel free-runs (wrong answer, visible
// in absmax) instead of hanging the container.
#define SPIN_CAP 40000

typedef __bf16 bf16x8 __attribute__((ext_vector_type(8)));
typedef float  f32x4  __attribute__((ext_vector_type(4)));

// ---------------- fast gate functions (v_exp_f32 = 2^x, v_rcp_f32) ----------------
__device__ __forceinline__ float fast_sigm(float x) {
    float e = __builtin_amdgcn_exp2f(-1.442695040889f * x);
    return __builtin_amdgcn_rcpf(1.0f + e);
}
__device__ __forceinline__ float fast_tanh(float x) {
    float e = __builtin_amdgcn_exp2f(2.885390081777f * x);
    return 1.0f - 2.0f * __builtin_amdgcn_rcpf(1.0f + e);
}

// ---------------- cast fp32 -> bf16 (plain) ----------------
__global__ void cast_f32_bf16(const float* __restrict__ in,
                              __bf16* __restrict__ out, int n) {
    int i = blockIdx.x * 256 + threadIdx.x;
    if (i < n) out[i] = (__bf16)in[i];
}

// ---------------- weight prepack ----------------
// dst row' = jb*64 + g*16 + jj  <->  orig gate-row = g*512 + jb*16 + jj
// dst row k-layout = [ w_ih (KIN) ; w_hh (512) ]   (bf16, plain)
__global__ void pack_w_kernel(const float* __restrict__ wih,
                              const float* __restrict__ whh,
                              __bf16* __restrict__ dst, int KIN) {
    int idx = blockIdx.x * 256 + threadIdx.x;
    int KE8 = (KIN + 512) >> 3;
    int total = 2048 * KE8;
    if (idx >= total) return;
    int row = idx / KE8, k8 = idx - row * KE8;
    int jb = row >> 6, g = (row >> 4) & 3, jj = row & 15;
    int orig = g * 512 + jb * 16 + jj;
    int k = k8 * 8;
    const float* src = (k < KIN) ? (wih + (size_t)orig * KIN + k)
                                 : (whh + (size_t)orig * 512 + (k - KIN));
    __bf16* d = dst + (size_t)row * (KIN + 512) + k;
    #pragma unroll
    for (int i = 0; i < 8; ++i) d[i] = (__bf16)src[i];
}

// ---------------- global -> LDS staging (linear, chunk-padded 1024->1040) ----------------
// 4 waves split nchunk 1024B chunks; chunk c lands at c*1040 in LDS.
__device__ __forceinline__ void stage_tile(char* lds, const char* g, int nchunk,
                                           int wv, int l) {
    const int per = nchunk >> 2;
    const char* gp = g + (size_t)l * 16;
    for (int i = 0; i < per; ++i) {
        int c = wv * per + i;
        __builtin_amdgcn_global_load_lds(
            (const __attribute__((address_space(1))) void*)(gp + c * 1024),
            (__attribute__((address_space(3))) void*)(lds + c * 1040),
            16, 0, 0);
    }
}

// ---------------- one LSTM layer, persistent (template: KX = KIN/32) ----------------
// 4 waves; wave wv computes gate wv (16 gate-rows) for 32 batch rows.
template <int KX>
__device__ __forceinline__ void run_layer(
    const __bf16* __restrict__ xsrc,   // [T][B][KX*32] plain bf16
    const __bf16* __restrict__ pw,     // [2048][KX*32+512] packed bf16
    const float*  __restrict__ bias,   // [2048] gate order i,f,g,o
    __bf16*       __restrict__ hout,   // [T][B][512] plain bf16
    int* ctr, int grp, int jb, int tid, int gbase, bool same,
    char* s_x, char* s_h, float (*s_g)[32][18])
{
    const int wv = tid >> 6, l = tid & 63;
    const int KE = KX * 32 + 512;

    // ---- weights -> VGPRs (per wave: 16 gate-rows x K; B-frag native layout) ----
    bf16x8 w[KX + 16];
    {
        const __bf16* rp = pw + (size_t)(jb * 64 + wv * 16 + (l & 15)) * KE + (l >> 4) * 8;
        #pragma unroll
        for (int kk = 0; kk < KX + 16; ++kk)
            w[kk] = *(const bf16x8*)(rp + kk * 32);
    }

    // ---- bias + cell state in registers (2 elements/thread) ----
    const int eb = tid >> 3;          // batch-local 0..31
    const int ej = (tid & 7) * 2;     // hidden-local 0..14 step 2
    float br[4][2], cc[2];
    #pragma unroll
    for (int g = 0; g < 4; ++g) {
        br[g][0] = bias[g * 512 + jb * 16 + ej];
        br[g][1] = bias[g * 512 + jb * 16 + ej + 1];
    }
    cc[0] = cc[1] = 0.0f;

    // ---- per-lane LDS fragment base offsets (chunk-padded: stride 1040) ----
    const int Cq = (l >> 4) * 16;
    const int row0 = (l & 15), row1 = 16 + (l & 15);
    int xoff0, xoff1;
    if (KX == 4) {   // 256B rows, 4 per chunk
        xoff0 = (row0 >> 2) * 1040 + (row0 & 3) * 256 + Cq;
        xoff1 = (row1 >> 2) * 1040 + (row1 & 3) * 256 + Cq;
    } else {         // 1024B rows, 1 per chunk
        xoff0 = row0 * 1040 + Cq;
        xoff1 = row1 * 1040 + Cq;
    }
    const int hoff0 = row0 * 1040 + Cq, hoff1 = row1 * 1040 + Cq;

    const size_t xrow = (size_t)KX * 64;   // bytes per batch-row of x

    // prologue: stage x(0), wait
    stage_tile(s_x, (const char*)xsrc + (size_t)(grp * 32) * xrow, KX * 2, wv, l);
    __syncthreads();

    for (int t = 0; t < TT; ++t) {
        // issue h(t-1) stage, then hide its latency under the x-contribution MFMAs
        if (t > 0)
            stage_tile(s_h, (const char*)hout + (size_t)((t - 1) * 256 + grp * 32) * 1024,
                       32, wv, l);

        f32x4 acc[2] = {};
        #pragma unroll
        for (int kk = 0; kk < KX; ++kk) {
            bf16x8 a0 = *(const bf16x8*)(s_x + xoff0 + kk * 64);
            bf16x8 a1 = *(const bf16x8*)(s_x + xoff1 + kk * 64);
            acc[0] = __builtin_amdgcn_mfma_f32_16x16x32_bf16(a0, w[kk], acc[0], 0, 0, 0);
            acc[1] = __builtin_amdgcn_mfma_f32_16x16x32_bf16(a1, w[kk], acc[1], 0, 0, 0);
        }
        __syncthreads();   // h(t-1) staged (each wave drains its own vmcnt at barrier)
        if (t > 0) {
            #pragma unroll
            for (int kk = 0; kk < 16; ++kk) {
                bf16x8 a0 = *(const bf16x8*)(s_h + hoff0 + kk * 64);
                bf16x8 a1 = *(const bf16x8*)(s_h + hoff1 + kk * 64);
                acc[0] = __builtin_amdgcn_mfma_f32_16x16x32_bf16(a0, w[KX + kk], acc[0], 0, 0, 0);
                acc[1] = __builtin_amdgcn_mfma_f32_16x16x32_bf16(a1, w[KX + kk], acc[1], 0, 0, 0);
            }
        }

        // ---- gate exchange (wave wv = gate wv) ----
        #pragma unroll
        for (int mt = 0; mt < 2; ++mt)
            #pragma unroll
            for (int r = 0; r < 4; ++r)
                s_g[wv][mt * 16 + (l >> 4) * 4 + r][l & 15] = acc[mt][r];
        __syncthreads();

        // ---- elementwise cell update; c lives in registers ----
        union { __bf16 h2[2]; unsigned u; } pk;
        #pragma unroll
        for (int q = 0; q < 2; ++q) {
            float xi = s_g[0][eb][ej + q] + br[0][q];
            float xf = s_g[1][eb][ej + q] + br[1][q];
            float xg = s_g[2][eb][ej + q] + br[2][q];
            float xo = s_g[3][eb][ej + q] + br[3][q];
            float iv = fast_sigm(xi), fv = fast_sigm(xf);
            float gv = fast_tanh(xg), ov = fast_sigm(xo);
            cc[q] = (t == 0) ? iv * gv : fmaf(fv, cc[q], iv * gv);
            pk.h2[q] = (__bf16)(ov * fast_tanh(cc[q]));
        }
        *(unsigned*)((char*)hout +
                  (size_t)((t * 256 + grp * 32 + eb) * 512 + jb * 16 + ej) * 2) = pk.u;

        // ---- group barrier (32 same-XCD blocks); x(t+1) prefetch overlaps spin ----
        if (!same) __threadfence();      // cross-XCD release (fallback only)
        __syncthreads();                 // vmcnt(0) drain: h-store visible in L2
        if (tid == 0)
            __hip_atomic_fetch_add(ctr, 1, __ATOMIC_RELAXED, __HIP_MEMORY_SCOPE_AGENT);
        if (t + 1 < TT)
            stage_tile(s_x, (const char*)xsrc + (size_t)((t + 1) * 256 + grp * 32) * xrow,
                       KX * 2, wv, l);
        if (tid == 0) {
            int tgt = 32 * (gbase + t + 1);
            int spins = 0;
            while (__hip_atomic_load(ctr, __ATOMIC_RELAXED, __HIP_MEMORY_SCOPE_AGENT) < tgt) {
                __builtin_amdgcn_s_sleep(1);
                if (++spins > SPIN_CAP) break;   // bounded: fail visibly, never hang
            }
        }
        __syncthreads();
        if (!same) __threadfence();      // cross-XCD acquire (fallback only)
    }
}

// ---------------- persistent 3-layer LSTM kernel ----------------
// LDS deliberately >80KB so exactly 1 block/CU -> 256 blocks cover all CUs
// -> every XCD hosts exactly 32 blocks (dynamic regrouping relies on this).
__global__ __launch_bounds__(256, 1) void lstm_persist(
    const __bf16* __restrict__ xb,
    const __bf16* __restrict__ pw0, const __bf16* __restrict__ pw1,
    const __bf16* __restrict__ pw2,
    const float* __restrict__ b0, const float* __restrict__ b1,
    const float* __restrict__ b2,
    __bf16* __restrict__ h0, __bf16* __restrict__ h1, __bf16* __restrict__ h2,
    int* ctrA, int* hs)
{
    __shared__ __align__(16) char s_x[41600];   // 32 used chunks @1040B (+pad to force 1 blk/CU)
    __shared__ __align__(16) char s_h[41600];
    __shared__ float s_g[4][32][18];
    __shared__ int s_grp, s_jb, s_same;

    const int tid = threadIdx.x;

    // ---- dynamic XCD regrouping: group = PHYSICAL XCD, jb = arrival slot ----
    // hs[0..7]: per-XCD block counts; hs[8]: total arrivals.
    if (tid == 0) {
        unsigned xcc = 0;
        asm volatile("s_getreg_b32 %0, hwreg(HW_REG_XCC_ID)" : "=s"(xcc));
        xcc &= 7;
        int slot = __hip_atomic_fetch_add(hs + xcc, 1, __ATOMIC_RELAXED,
                                          __HIP_MEMORY_SCOPE_AGENT);
        __hip_atomic_fetch_add(hs + 8, 1, __ATOMIC_RELEASE, __HIP_MEMORY_SCOPE_AGENT);
        int spins = 0;
        while (__hip_atomic_load(hs + 8, __ATOMIC_ACQUIRE, __HIP_MEMORY_SCOPE_AGENT) < 256) {
            __builtin_amdgcn_s_sleep(1);
            if (++spins > SPIN_CAP) break;       // bounded: fail visibly, never hang
        }
        int ok = 1;
        #pragma unroll
        for (int x = 0; x < 8; ++x)
            ok &= (__hip_atomic_load(hs + x, __ATOMIC_RELAXED,
                                     __HIP_MEMORY_SCOPE_AGENT) == 32);
        s_same = ok;
        s_grp = ok ? (int)xcc : (int)(blockIdx.x & 7);
        s_jb  = ok ? slot     : (int)(blockIdx.x >> 3);
    }
    __syncthreads();
    const bool same = (s_same != 0);
    const int  grp  = s_grp, jb = s_jb;

    run_layer<4>(xb, pw0, b0, h0, ctrA + grp * 64, grp, jb, tid, 0, same, s_x, s_h, s_g);
    run_layer<16>(h0, pw1, b1, h1, ctrA + grp * 64, grp, jb, tid, 256, same, s_x, s_h, s_g);
    run_layer<16>(h1, pw2, b2, h2, ctrA + grp * 64, grp, jb, tid, 512, same, s_x, s_h, s_g);
}

// ---------------- final projection (h2 is plain [8192, HH]) ----------------
__global__ __launch_bounds__(256) void proj_kernel(
    const __bf16* __restrict__ A,    // [8192, HH]
    const __bf16* __restrict__ Wo,   // [OO, HH]
    const float*  __restrict__ bo,   // [OO]
    float*        __restrict__ out)  // [8192, OO]
{
    const int r0   = blockIdx.x * 32;
    const int wave = threadIdx.x >> 6;
    const int lane = threadIdx.x & 63;
    const int n0   = wave * 32;
    const int arow = lane & 15;
    const int koff = (lane >> 4) * 8;

    f32x4 acc[2][2] = {};
    const __bf16* a0p = A  + (size_t)(r0 + arow) * HH + koff;
    const __bf16* a1p = A  + (size_t)(r0 + 16 + arow) * HH + koff;
    const __bf16* w0p = Wo + (size_t)(n0 + arow) * HH + koff;
    const __bf16* w1p = Wo + (size_t)(n0 + 16 + arow) * HH + koff;
    for (int k0 = 0; k0 < HH; k0 += 32) {
        bf16x8 a0 = *(const bf16x8*)(a0p + k0);
        bf16x8 a1 = *(const bf16x8*)(a1p + k0);
        bf16x8 w0 = *(const bf16x8*)(w0p + k0);
        bf16x8 w1 = *(const bf16x8*)(w1p + k0);
        acc[0][0] = __builtin_amdgcn_mfma_f32_16x16x32_bf16(a0, w0, acc[0][0], 0, 0, 0);
        acc[0][1] = __builtin_amdgcn_mfma_f32_16x16x32_bf16(a0, w1, acc[0][1], 0, 0, 0);
        acc[1][0] = __builtin_amdgcn_mfma_f32_16x16x32_bf16(a1, w0, acc[1][0], 0, 0, 0);
        acc[1][1] = __builtin_amdgcn_mfma_f32_16x16x32_bf16(a1, w1, acc[1][1], 0, 0, 0);
    }
    #pragma unroll
    for (int mi = 0; mi < 2; ++mi)
        #pragma unroll
        for (int ni = 0; ni < 2; ++ni)
            #pragma unroll
            for (int r = 0; r < 4; ++r) {
                int row = r0 + mi * 16 + ((lane >> 4) * 4) + r;
                int col = n0 + ni * 16 + (lane & 15);
                out[(size_t)row * OO + col] = acc[mi][ni][r] + bo[col];
            }
}

// ---------------- launch ----------------
extern "C" void kernel_launch(void* const* d_in, const int* in_sizes, int n_in,
                              void* d_out, int out_size, void* d_ws, size_t ws_size,
                              hipStream_t stream) {
    const float* x      = (const float*)d_in[0];
    const float* w_ih_0 = (const float*)d_in[1];
    const float* w_hh_0 = (const float*)d_in[2];
    const float* b_0    = (const float*)d_in[3];
    const float* w_ih_1 = (const float*)d_in[4];
    const float* w_hh_1 = (const float*)d_in[5];
    const float* b_1    = (const float*)d_in[6];
    const float* w_ih_2 = (const float*)d_in[7];
    const float* w_hh_2 = (const float*)d_in[8];
    const float* b_2    = (const float*)d_in[9];
    const float* w_out  = (const float*)d_in[10];
    const float* b_out  = (const float*)d_in[11];
    float* out = (float*)d_out;

    // ---- workspace carve-up ----
    char* ws = (char*)d_ws;
    size_t off = 0;
    __bf16* xb    = (__bf16*)(ws + off); off += (size_t)TT * BB * II * 2;      // 16.8 MB
    __bf16* pw0   = (__bf16*)(ws + off); off += (size_t)2048 * 640 * 2;        // 2.6 MB
    __bf16* pw1   = (__bf16*)(ws + off); off += (size_t)2048 * 1024 * 2;       // 4.2 MB
    __bf16* pw2   = (__bf16*)(ws + off); off += (size_t)2048 * 1024 * 2;
    __bf16* woutb = (__bf16*)(ws + off); off += (size_t)OO * HH * 2;
    __bf16* h0    = (__bf16*)(ws + off); off += (size_t)TT * BB * HH * 2;      // 67 MB
    __bf16* h1    = (__bf16*)(ws + off); off += (size_t)TT * BB * HH * 2;
    __bf16* h2    = (__bf16*)(ws + off); off += (size_t)TT * BB * HH * 2;
    int*    ctrA  = (int*)(ws + off);    off += (size_t)8 * 64 * 4;
    int*    hs    = (int*)(ws + off);    off += (size_t)64 * 4;
    (void)ws_size; (void)in_sizes; (void)n_in; (void)out_size;

    // ---- prepack ----
    {
        int n = TT * BB * II;
        cast_f32_bf16<<<(n + 255) / 256, 256, 0, stream>>>(x, xb, n);
        n = OO * HH;
        cast_f32_bf16<<<(n + 255) / 256, 256, 0, stream>>>(w_out, woutb, n);
        int t0 = 2048 * (640 / 8);
        pack_w_kernel<<<(t0 + 255) / 256, 256, 0, stream>>>(w_ih_0, w_hh_0, pw0, II);
        int t1 = 2048 * (1024 / 8);
        pack_w_kernel<<<(t1 + 255) / 256, 256, 0, stream>>>(w_ih_1, w_hh_1, pw1, HH);
        pack_w_kernel<<<(t1 + 255) / 256, 256, 0, stream>>>(w_ih_2, w_hh_2, pw2, HH);
    }
    hipMemsetAsync(ctrA, 0, (size_t)(8 * 64 + 64) * 4, stream);

    // ---- persistent 3-layer LSTM: 256 blocks (1/CU), XCD-local groups ----
    lstm_persist<<<256, 256, 0, stream>>>(xb, pw0, pw1, pw2, b_0, b_1, b_2,
                                          h0, h1, h2, ctrA, hs);

    // ---- projection over last WW timesteps ----
    const __bf16* A = h2 + (size_t)(TT - WW) * BB * HH;
    proj_kernel<<<(WW * BB) / 32, 256, 0, stream>>>(A, woutb, b_out, out);
}